// Round 1
// baseline (368.230 us; speedup 1.0000x reference)
//
#include <hip/hip_runtime.h>
#include <hip/hip_bf16.h>

#define N_NODES 150000
#define CDIM 256
#define DIM 256

typedef float f32x4 __attribute__((ext_vector_type(4)));
typedef short bf16x8 __attribute__((ext_vector_type(8)));

// ws layout (bytes)
#define WS_CB 0          // bf16 B fragments: [32][256][8] ushort = 131072 B
#define WS_SC 131072     // sc[256] f32
#define WS_GACC 132096   // gacc[256] f32
#define WS_MSUM 133120   // masksum[1] f32

__device__ __forceinline__ unsigned short f2bf(float f) {
  unsigned u = __float_as_uint(f);
  u += 0x7FFFu + ((u >> 16) & 1u);   // round-to-nearest-even
  return (unsigned short)(u >> 16);
}

// blocks 0..255: centroid row b -> bf16 frag layout + sc[b]
// blocks 256..319: grid-stride sum of mask -> msum
__global__ void cd_prep(const float* __restrict__ cw, const float* __restrict__ mask,
                        unsigned short* __restrict__ cb, float* __restrict__ sc,
                        float* __restrict__ msum) {
  int b = blockIdx.x;
  int t = threadIdx.x;
  int wave = t >> 6, lane = t & 63;
  __shared__ float red[4];
  if (b < CDIM) {
    float v = cw[b * DIM + t];
    // fragment-major: cb[(k>>3)][b][k&7] ; (k>>3) = kt*4+q
    cb[(size_t)(t >> 3) * (CDIM * 8) + b * 8 + (t & 7)] = f2bf(v);
    float ss = v * v;
    #pragma unroll
    for (int off = 32; off >= 1; off >>= 1) ss += __shfl_xor(ss, off);
    if (lane == 0) red[wave] = ss;
    __syncthreads();
    if (t == 0) sc[b] = red[0] + red[1] + red[2] + red[3];
  } else {
    int idx = (b - CDIM) * 256 + t;
    const int stride = 64 * 256;
    float s = 0.f;
    for (int i = idx; i < N_NODES; i += stride) s += mask[i];
    #pragma unroll
    for (int off = 32; off >= 1; off >>= 1) s += __shfl_xor(s, off);
    if (lane == 0) red[wave] = s;
    __syncthreads();
    if (t == 0) atomicAdd(msum, red[0] + red[1] + red[2] + red[3]);
  }
}

__global__ __launch_bounds__(256, 2)
void cd_main(const float* __restrict__ x, const float* __restrict__ mask,
             const unsigned short* __restrict__ cb, const float* __restrict__ sc,
             float* __restrict__ gacc, float* __restrict__ out1) {
  const int lane = threadIdx.x & 63;
  const int w = threadIdx.x >> 6;
  const int q = lane >> 4;
  const int ln = lane & 15;
  const long m0 = (long)blockIdx.x * 64;
  const int c0 = w * 64;

  f32x4 acc[4][4] = {};
  float spart[4] = {0.f, 0.f, 0.f, 0.f};

  for (int kt = 0; kt < 8; ++kt) {
    bf16x8 bf[4];
    #pragma unroll
    for (int nt = 0; nt < 4; ++nt) {
      int col = c0 + nt * 16 + ln;
      bf[nt] = *(const bf16x8*)(cb + (size_t)(kt * 4 + q) * (CDIM * 8) + col * 8);
    }
    #pragma unroll
    for (int mt = 0; mt < 4; ++mt) {
      long row = m0 + mt * 16 + ln;
      long rg = row < N_NODES ? row : (long)(N_NODES - 1);
      const float* px = x + rg * DIM + kt * 32 + q * 8;
      f32x4 a0 = *(const f32x4*)px;
      f32x4 a1 = *(const f32x4*)(px + 4);
      spart[mt] += a0.x*a0.x + a0.y*a0.y + a0.z*a0.z + a0.w*a0.w
                 + a1.x*a1.x + a1.y*a1.y + a1.z*a1.z + a1.w*a1.w;
      bf16x8 af;
      af[0] = (short)f2bf(a0.x); af[1] = (short)f2bf(a0.y);
      af[2] = (short)f2bf(a0.z); af[3] = (short)f2bf(a0.w);
      af[4] = (short)f2bf(a1.x); af[5] = (short)f2bf(a1.y);
      af[6] = (short)f2bf(a1.z); af[7] = (short)f2bf(a1.w);
      #pragma unroll
      for (int nt = 0; nt < 4; ++nt)
        acc[mt][nt] = __builtin_amdgcn_mfma_f32_16x16x32_bf16(af, bf[nt], acc[mt][nt], 0, 0, 0);
    }
  }

  // sx per row: spart holds quarter-sums for row (ln + 16*mt), k-subset q
  float sxv[4];
  #pragma unroll
  for (int mt = 0; mt < 4; ++mt) {
    float s = spart[mt];
    s += __shfl_xor(s, 16);
    s += __shfl_xor(s, 32);
    sxv[mt] = s;             // = sx[m0 + mt*16 + ln], valid on all lanes
  }

  float scv[4], rcv[4];
  #pragma unroll
  for (int nt = 0; nt < 4; ++nt) {
    scv[nt] = sc[c0 + nt * 16 + ln];
    rcv[nt] = 1.0f - scv[nt];
  }

  float pc[4] = {0.f, 0.f, 0.f, 0.f};
  #pragma unroll
  for (int mt = 0; mt < 4; ++mt) {
    float sxe[4], rxe[4], mke[4];
    long rows[4];
    #pragma unroll
    for (int i = 0; i < 4; ++i) {
      int rloc = q * 4 + i;                       // C/D: row = 4*(lane>>4)+reg
      sxe[i] = __shfl(sxv[mt], rloc);             // fetch sx of that row
      rows[i] = m0 + mt * 16 + rloc;
      mke[i] = (rows[i] < N_NODES) ? mask[rows[i]] : 0.f;
      rxe[i] = 1.0f - sxe[i];
    }
    #pragma unroll
    for (int nt = 0; nt < 4; ++nt) {
      int col = c0 + nt * 16 + ln;                // C/D: col = lane&15
      #pragma unroll
      for (int i = 0; i < 4; ++i) {
        float xc = acc[mt][nt][i];
        float sq = fmaf(-2.0f, xc, sxe[i] + scv[nt]);
        sq = fmaxf(sq, 0.0f);
        float den = fmaxf(rxe[i] * rcv[nt], 1e-12f);
        float z = 1.0f + __fdividef(2.0f * sq, den);
        z = fmaxf(z, 1.0f + 1e-7f);
        float t2 = z + sqrtf(fmaf(z, z, -1.0f));
        float dd = __log2f(t2) * 0.6931471805599453f;
        float o = dd * mke[i];
        if (rows[i] < N_NODES) out1[rows[i] * CDIM + col] = o;
        pc[nt] += o;
      }
    }
  }

  #pragma unroll
  for (int nt = 0; nt < 4; ++nt) {
    float s = pc[nt];
    s += __shfl_xor(s, 16);
    s += __shfl_xor(s, 32);
    if (lane < 16) atomicAdd(gacc + c0 + nt * 16 + ln, s);
  }
}

__global__ void cd_final(const float* __restrict__ gacc, const float* __restrict__ msum,
                         float* __restrict__ out0) {
  int t = threadIdx.x;
  out0[t] = gacc[t] / msum[0];
}

extern "C" void kernel_launch(void* const* d_in, const int* in_sizes, int n_in,
                              void* d_out, int out_size, void* d_ws, size_t ws_size,
                              hipStream_t stream) {
  const float* x    = (const float*)d_in[0];   // [150000,256]
  const float* mask = (const float*)d_in[1];   // [150000,1]
  const float* cw   = (const float*)d_in[2];   // [256,256]
  float* out = (float*)d_out;                  // [256] ++ [150000*256]
  char* ws = (char*)d_ws;
  unsigned short* cb = (unsigned short*)(ws + WS_CB);
  float* sc   = (float*)(ws + WS_SC);
  float* gacc = (float*)(ws + WS_GACC);
  float* msum = (float*)(ws + WS_MSUM);

  // zero gacc + msum (ws is poisoned before every call)
  hipMemsetAsync(ws + WS_GACC, 0, 256 * 4 + 4, stream);
  cd_prep<<<320, 256, 0, stream>>>(cw, mask, cb, sc, msum);
  const int nblocks = (N_NODES + 63) / 64;     // 2344
  cd_main<<<nblocks, 256, 0, stream>>>(x, mask, cb, sc, gacc, out + 256);
  cd_final<<<1, 256, 0, stream>>>(gacc, msum, out);
}

// Round 2
// 327.877 us; speedup vs baseline: 1.1231x; 1.1231x over previous
//
#include <hip/hip_runtime.h>
#include <hip/hip_bf16.h>

#define N_NODES 150000
#define CDIM 256
#define DIM 256

typedef float f32x4 __attribute__((ext_vector_type(4)));
typedef short bf16x8 __attribute__((ext_vector_type(8)));
typedef unsigned short u16x4 __attribute__((ext_vector_type(4)));

// ws layout (bytes)
#define WS_CB 0          // bf16 B fragments: [32][256][8] ushort = 131072 B
#define WS_SC 131072     // sc[256] f32
#define WS_GACC 132096   // gacc[256] f32
#define WS_MSUM 133120   // masksum[1] f32

__device__ __forceinline__ unsigned short f2bf(float f) {
  unsigned u = __float_as_uint(f);
  u += 0x7FFFu + ((u >> 16) & 1u);   // round-to-nearest-even
  return (unsigned short)(u >> 16);
}

// blocks 0..255: centroid row b -> bf16 frag layout + sc[b]
// blocks 256..319: grid-stride sum of mask -> msum
__global__ void cd_prep(const float* __restrict__ cw, const float* __restrict__ mask,
                        unsigned short* __restrict__ cb, float* __restrict__ sc,
                        float* __restrict__ msum) {
  int b = blockIdx.x;
  int t = threadIdx.x;
  int wave = t >> 6, lane = t & 63;
  __shared__ float red[4];
  if (b < CDIM) {
    float v = cw[b * DIM + t];
    // fragment-major: cb[(k>>3)][b][k&7]
    cb[(size_t)(t >> 3) * (CDIM * 8) + b * 8 + (t & 7)] = f2bf(v);
    float ss = v * v;
    #pragma unroll
    for (int off = 32; off >= 1; off >>= 1) ss += __shfl_xor(ss, off);
    if (lane == 0) red[wave] = ss;
    __syncthreads();
    if (t == 0) sc[b] = red[0] + red[1] + red[2] + red[3];
  } else {
    int idx = (b - CDIM) * 256 + t;
    const int stride = 64 * 256;
    float s = 0.f;
    for (int i = idx; i < N_NODES; i += stride) s += mask[i];
    #pragma unroll
    for (int off = 32; off >= 1; off >>= 1) s += __shfl_xor(s, off);
    if (lane == 0) red[wave] = s;
    __syncthreads();
    if (t == 0) atomicAdd(msum, red[0] + red[1] + red[2] + red[3]);
  }
}

__global__ __launch_bounds__(256, 4)
void cd_main(const float* __restrict__ x, const float* __restrict__ mask,
             const unsigned short* __restrict__ cb, const float* __restrict__ sc,
             float* __restrict__ gacc, float* __restrict__ out1) {
  // A-tile bf16 fragments: [k>>3][row][k&7] = [32][64][8] ushort = 32 KB.
  // Bank math: every wave-wide ds access spreads uniformly over all 32 banks
  // (1 KB b128 read = 8-round floor, 512 B b64 write = 4-round floor) -> no
  // excess conflicts, no swizzle needed.
  __shared__ unsigned short ab[32 * 64 * 8];
  __shared__ float sxl[64];

  const int t = threadIdx.x;
  const long m0 = (long)blockIdx.x * 64;

  // ---- stage x-tile -> LDS (coalesced, convert once, exact f32 sx) ----
  {
    const int row = t >> 2;          // 0..63
    const int qq  = t & 3;           // column quarter
    const long grow = m0 + row;
    const bool ok = grow < N_NODES;
    const float* px = x + grow * DIM;
    float ss = 0.f;
    #pragma unroll
    for (int i = 0; i < 16; ++i) {
      const int col4 = qq * 4 + i * 16;     // 4 consecutive k's
      f32x4 v;
      if (ok) v = *(const f32x4*)(px + col4);
      else    v = f32x4{0.f, 0.f, 0.f, 0.f};
      ss = fmaf(v.x, v.x, ss); ss = fmaf(v.y, v.y, ss);
      ss = fmaf(v.z, v.z, ss); ss = fmaf(v.w, v.w, ss);
      u16x4 b;
      b[0] = f2bf(v.x); b[1] = f2bf(v.y); b[2] = f2bf(v.z); b[3] = f2bf(v.w);
      *(u16x4*)(ab + ((size_t)(col4 >> 3) * 64 + row) * 8 + (col4 & 7)) = b;
    }
    ss += __shfl_xor(ss, 1);
    ss += __shfl_xor(ss, 2);
    if (qq == 0) sxl[row] = ss;
  }
  __syncthreads();

  // ---- MFMA: wave w owns 64 rows x 64 cols (c0 = w*64) ----
  const int lane = t & 63;
  const int w = t >> 6;
  const int q = lane >> 4;
  const int ln = lane & 15;
  const int c0 = w * 64;

  f32x4 acc[4][4] = {};
  #pragma unroll
  for (int kt = 0; kt < 8; ++kt) {
    bf16x8 bf[4];
    #pragma unroll
    for (int nt = 0; nt < 4; ++nt)
      bf[nt] = *(const bf16x8*)(cb + (size_t)(kt * 4 + q) * (CDIM * 8) + (c0 + nt * 16 + ln) * 8);
    #pragma unroll
    for (int mt = 0; mt < 4; ++mt) {
      bf16x8 af = *(const bf16x8*)(ab + ((size_t)(kt * 4 + q) * 64 + mt * 16 + ln) * 8);
      #pragma unroll
      for (int nt = 0; nt < 4; ++nt)
        acc[mt][nt] = __builtin_amdgcn_mfma_f32_16x16x32_bf16(af, bf[nt], acc[mt][nt], 0, 0, 0);
    }
  }

  // ---- epilogue: arccosh distance, mask, store, column partials ----
  float scv[4], rcv[4];
  #pragma unroll
  for (int nt = 0; nt < 4; ++nt) {
    scv[nt] = sc[c0 + nt * 16 + ln];
    rcv[nt] = 1.0f - scv[nt];
  }

  float pc[4] = {0.f, 0.f, 0.f, 0.f};
  #pragma unroll
  for (int mt = 0; mt < 4; ++mt) {
    float sxe[4], rxe[4], mke[4];
    long rows[4];
    #pragma unroll
    for (int i = 0; i < 4; ++i) {
      const int rloc = q * 4 + i;                 // C/D: row = 4*(lane>>4)+reg
      sxe[i] = sxl[mt * 16 + rloc];
      rows[i] = m0 + mt * 16 + rloc;
      mke[i] = (rows[i] < N_NODES) ? mask[rows[i]] : 0.f;
      rxe[i] = 1.0f - sxe[i];
    }
    #pragma unroll
    for (int nt = 0; nt < 4; ++nt) {
      const int col = c0 + nt * 16 + ln;          // C/D: col = lane&15
      #pragma unroll
      for (int i = 0; i < 4; ++i) {
        float xc = acc[mt][nt][i];
        float sq = fmaf(-2.0f, xc, sxe[i] + scv[nt]);
        sq = fmaxf(sq, 0.0f);
        float den = fmaxf(rxe[i] * rcv[nt], 1e-12f);
        float z = 1.0f + __fdividef(2.0f * sq, den);
        z = fmaxf(z, 1.0f + 1e-7f);
        float t2 = z + sqrtf(fmaf(z, z, -1.0f));
        float dd = __log2f(t2) * 0.6931471805599453f;
        float o = dd * mke[i];
        if (rows[i] < N_NODES) out1[rows[i] * CDIM + col] = o;
        pc[nt] += o;
      }
    }
  }

  #pragma unroll
  for (int nt = 0; nt < 4; ++nt) {
    float s = pc[nt];
    s += __shfl_xor(s, 16);
    s += __shfl_xor(s, 32);
    if (lane < 16) atomicAdd(gacc + c0 + nt * 16 + ln, s);
  }
}

__global__ void cd_final(const float* __restrict__ gacc, const float* __restrict__ msum,
                         float* __restrict__ out0) {
  int t = threadIdx.x;
  out0[t] = gacc[t] / msum[0];
}

extern "C" void kernel_launch(void* const* d_in, const int* in_sizes, int n_in,
                              void* d_out, int out_size, void* d_ws, size_t ws_size,
                              hipStream_t stream) {
  const float* x    = (const float*)d_in[0];   // [150000,256]
  const float* mask = (const float*)d_in[1];   // [150000,1]
  const float* cw   = (const float*)d_in[2];   // [256,256]
  float* out = (float*)d_out;                  // [256] ++ [150000*256]
  char* ws = (char*)d_ws;
  unsigned short* cb = (unsigned short*)(ws + WS_CB);
  float* sc   = (float*)(ws + WS_SC);
  float* gacc = (float*)(ws + WS_GACC);
  float* msum = (float*)(ws + WS_MSUM);

  hipMemsetAsync(ws + WS_GACC, 0, 256 * 4 + 4, stream);
  cd_prep<<<320, 256, 0, stream>>>(cw, mask, cb, sc, msum);
  const int nblocks = (N_NODES + 63) / 64;     // 2344
  cd_main<<<nblocks, 256, 0, stream>>>(x, mask, cb, sc, gacc, out + 256);
  cd_final<<<1, 256, 0, stream>>>(gacc, msum, out);
}